// Round 1
// baseline (16221.149 us; speedup 1.0000x reference)
//
#include <hip/hip_runtime.h>
#include <stdint.h>

#define N_NEUR 4096
#define N_IN   512
#define BATCH  8
#define TSTEPS 1000
#define STRIDE_OUT (BATCH * TSTEPS * N_NEUR)   // 32,768,000 elements per output tensor

// exp(-1/20), exp(-1/10), exp(-1/5) — full-precision decimals, rounded to f32 by compiler
#define BETA_E_F 0.95122942450071400910f
#define BETA_I_F 0.90483741803595957316f
#define ALPHA_F  0.81873075307798185867f
#define RC_E_F   (100.0f * (1.0f - BETA_E_F))  // R*(1-beta), folded in f32
#define RC_I_F   (100.0f * (1.0f - BETA_I_F))
#define U_REST_F  (-65.0f)
#define THETA_F   (-50.0f)
#define U_RESET_F (-65.0f)

// Device-global scratch (avoids reliance on unknown ws_size; rewritten every call)
__device__ __attribute__((aligned(16))) uint16_t g_W[N_NEUR * N_NEUR];     // bf16, pre-scaled, stripe-packed [stripe][row4096][col16]
__device__ __attribute__((aligned(16))) float    g_FF[256 * N_IN * 16];    // f32, stripe-packed [stripe][row512][col16]
__device__ uint8_t  g_inb[TSTEPS * N_IN];   // input spike bits, bit b = batch b
__device__ uint32_t g_ring[2 * N_NEUR];     // double-buffered spike bits, bit b = batch b
__device__ float    g_I[BATCH * N_NEUR];    // I state
__device__ float    g_vr[BATCH * N_NEUR];   // post-reset v state

__global__ void prep_w(const float* __restrict__ W, const int* __restrict__ types) {
    const int total = N_NEUR * N_NEUR;
    for (int o = blockIdx.x * 256 + threadIdx.x; o < total; o += gridDim.x * 256) {
        int stripe = o >> 16;            // 4096*16 elems per stripe
        int inner  = o & 65535;
        int row = inner >> 4, c = inner & 15;
        int col = stripe * 16 + c;
        float scale = (types[col] == 1) ? 0.5f : 2.0f;   // exact powers of 2
        float v = W[row * N_NEUR + col] * scale;
        uint32_t x = __float_as_uint(v);
        uint32_t r = x + 0x7FFFu + ((x >> 16) & 1u);     // RNE to bf16
        g_W[o] = (uint16_t)(r >> 16);
    }
}

__global__ void prep_ff(const float* __restrict__ FF) {
    const int total = 256 * N_IN * 16;
    for (int o = blockIdx.x * 256 + threadIdx.x; o < total; o += gridDim.x * 256) {
        int stripe = o >> 13;            // 512*16 elems per stripe
        int inner  = o & 8191;
        int row = inner >> 4, c = inner & 15;
        g_FF[o] = FF[row * N_NEUR + stripe * 16 + c];
    }
}

__global__ void prep_in(const float* __restrict__ inp) {
    const int total = TSTEPS * N_IN;
    for (int o = blockIdx.x * 256 + threadIdx.x; o < total; o += gridDim.x * 256) {
        int t = o >> 9, i = o & 511;
        uint32_t m = 0;
#pragma unroll
        for (int b = 0; b < 8; ++b) {
            float v = inp[(b * TSTEPS + t) * N_IN + i];
            m |= (v != 0.0f ? 1u : 0u) << b;
        }
        g_inb[o] = (uint8_t)m;
    }
}

// Step 0 boundary: v[1], s[1] from initial state; outputs tau=0 (s, v); seeds states + ring slot 1
__global__ void k_init(const float* __restrict__ v0p, const float* __restrict__ I0p,
                       const int* __restrict__ types, float* __restrict__ out) {
    int n = blockIdx.x * 256 + threadIdx.x;   // grid = 16 blocks -> n in [0,4096)
    bool exc = (types[n] == 1);
    float beta = exc ? BETA_E_F : BETA_I_F;
    float rc   = exc ? RC_E_F   : RC_I_F;
    uint32_t bits = 0;
#pragma unroll
    for (int b = 0; b < 8; ++b) {
        int gi = b * N_NEUR + n;
        float v0 = v0p[gi], I0 = I0p[gi];
        float v = U_REST_F + (v0 - U_REST_F) * beta + I0 * rc;
        bool s = (v >= THETA_F);
        float vr = s ? U_RESET_F : v;
        out[(b * TSTEPS + 0) * N_NEUR + n] = s ? 1.0f : 0.0f;
        out[STRIDE_OUT + (b * TSTEPS + 0) * N_NEUR + n] = vr;
        g_vr[gi] = vr;
        g_I[gi]  = I0;
        bits |= (s ? 1u : 0u) << b;
    }
    g_ring[1 * N_NEUR + n] = bits;
}

// K_t (t=1..1000): I[t] = alpha*I[t-1] + s[t]@Wscaled + inputs[t-1]@FF  (out I @ tau=t-1)
// then (t<1000): v[t+1], s[t+1], vr[t+1] for own cols (out s,v @ tau=t), publish s[t+1] bits.
__global__ void __launch_bounds__(256)
k_step(const int* __restrict__ types, float* __restrict__ out, int t) {
    __shared__ uint8_t sb[N_NEUR + N_IN];
    __shared__ float red[4][64][2];
    __shared__ unsigned long long wb[2];

    int tid = threadIdx.x;
    int blk = blockIdx.x;
    // XCD-aware swizzle: XCD x = blk&7 owns contiguous stripes [32x, 32x+32) => 4MB bf16 slab per XCD L2
    int stripe  = ((blk & 7) << 5) | (blk >> 3);
    int colbase = stripe << 4;

    // stage spike bits (4096) + input bits (512) for this step into LDS bytes
    {
        const uint32_t* rs = &g_ring[(t & 1) * N_NEUR];
        for (int i = tid; i < N_NEUR; i += 256) sb[i] = (uint8_t)rs[i];
        const uint8_t* ib = &g_inb[(t - 1) * N_IN];
        sb[N_NEUR + tid]       = ib[tid];
        sb[N_NEUR + 256 + tid] = ib[256 + tid];
    }
    __syncthreads();

    const int ch = tid & 1;       // column half (8 cols each)
    const int rg = tid >> 1;      // row group 0..127
    float acc[64];                // acc[b*8+c]
#pragma unroll
    for (int a = 0; a < 64; ++a) acc[a] = 0.0f;

    // recurrent part: 4096 rows of bf16 W (pre-scaled)
    {
        const uint4* wq = (const uint4*)g_W + (stripe * 8192 + rg * 2 + ch);
#pragma unroll 2
        for (int k = 0; k < 32; ++k) {
            uint4 q = wq[k * 256];
            int i = rg + (k << 7);
            uint32_t m = sb[i];
            float w[8];
            w[0] = __uint_as_float(q.x << 16); w[1] = __uint_as_float(q.x & 0xFFFF0000u);
            w[2] = __uint_as_float(q.y << 16); w[3] = __uint_as_float(q.y & 0xFFFF0000u);
            w[4] = __uint_as_float(q.z << 16); w[5] = __uint_as_float(q.z & 0xFFFF0000u);
            w[6] = __uint_as_float(q.w << 16); w[7] = __uint_as_float(q.w & 0xFFFF0000u);
#pragma unroll
            for (int b = 0; b < 8; ++b) {
                float sf = (float)((m >> b) & 1u);
#pragma unroll
                for (int c = 0; c < 8; ++c) acc[b * 8 + c] = fmaf(sf, w[c], acc[b * 8 + c]);
            }
        }
    }
    // feedforward part: 512 rows, kept f32 for step-2 spike-decision fidelity
    {
        const float4* fq = (const float4*)g_FF + (stripe * 2048 + rg * 4 + ch * 2);
#pragma unroll
        for (int k = 0; k < 4; ++k) {
            float4 q0 = fq[k * 512];
            float4 q1 = fq[k * 512 + 1];
            int i = rg + (k << 7);
            uint32_t m = sb[N_NEUR + i];
            float w[8] = {q0.x, q0.y, q0.z, q0.w, q1.x, q1.y, q1.z, q1.w};
#pragma unroll
            for (int b = 0; b < 8; ++b) {
                float sf = (float)((m >> b) & 1u);
#pragma unroll
                for (int c = 0; c < 8; ++c) acc[b * 8 + c] = fmaf(sf, w[c], acc[b * 8 + c]);
            }
        }
    }

    // recursive-halving wave reduction over 32 row groups (preserves ch parity; never swaps bit 0)
    int lane = tid & 63;
#pragma unroll
    for (int rnd = 0; rnd < 5; ++rnd) {
        int s = 2 << rnd;
        int h = 32 >> rnd;
        bool up = (lane & s) != 0;
#pragma unroll
        for (int a = 0; a < 32; ++a) {
            if (a < h) {
                float give = up ? acc[a] : acc[a + h];
                float got  = __shfl_xor(give, s, 64);
                float keep = up ? acc[a + h] : acc[a];
                acc[a] = keep + got;
            }
        }
    }
    int wv = tid >> 6;
    red[wv][lane][0] = acc[0];
    red[wv][lane][1] = acc[1];
    __syncthreads();

    // final: 128 threads own (batch b, local col nl)
    if (tid < 128) {
        int b = tid >> 4, nl = tid & 15;
        int a   = b * 8 + (nl & 7);
        int lch = nl >> 3;
        int ln  = lch | ((a & 32) ? 2 : 0) | ((a & 16) ? 4 : 0) | ((a & 8) ? 8 : 0)
                      | ((a & 4) ? 16 : 0) | ((a & 2) ? 32 : 0);
        int j = a & 1;
        float S = red[0][ln][j] + red[1][ln][j] + red[2][ln][j] + red[3][ln][j];
        int n  = colbase + nl;
        int gi = b * N_NEUR + n;
        float Inew = g_I[gi] * ALPHA_F + S;   // S = s@Wscaled + drive (FF rows included)
        out[2 * STRIDE_OUT + (b * TSTEPS + (t - 1)) * N_NEUR + n] = Inew;
        g_I[gi] = Inew;
        if (t < TSTEPS) {
            bool exc = (types[n] == 1);
            float beta = exc ? BETA_E_F : BETA_I_F;
            float rc   = exc ? RC_E_F   : RC_I_F;
            float vr = g_vr[gi];
            float v = U_REST_F + (vr - U_REST_F) * beta + Inew * rc;
            bool sbit = (v >= THETA_F);
            float vn = sbit ? U_RESET_F : v;
            out[(b * TSTEPS + t) * N_NEUR + n] = sbit ? 1.0f : 0.0f;
            out[STRIDE_OUT + (b * TSTEPS + t) * N_NEUR + n] = vn;
            g_vr[gi] = vn;
            unsigned long long bal = __ballot(sbit);   // wave0: b0..3, wave1: b4..7
            if ((tid & 63) == 0) wb[tid >> 6] = bal;
        }
    }
    __syncthreads();
    if (t < TSTEPS && tid < 16) {
        unsigned long long b0 = wb[0], b1 = wb[1];
        uint32_t bits = 0;
#pragma unroll
        for (int q = 0; q < 4; ++q) {
            bits |= (uint32_t)((b0 >> (tid + 16 * q)) & 1ull) << q;
            bits |= (uint32_t)((b1 >> (tid + 16 * q)) & 1ull) << (q + 4);
        }
        g_ring[((t + 1) & 1) * N_NEUR + colbase + tid] = bits;
    }
}

extern "C" void kernel_launch(void* const* d_in, const int* in_sizes, int n_in,
                              void* d_out, int out_size, void* d_ws, size_t ws_size,
                              hipStream_t stream) {
    const int*   types = (const int*)d_in[0];
    const float* Wrec  = (const float*)d_in[1];
    const float* FF    = (const float*)d_in[2];
    const float* inp   = (const float*)d_in[3];
    const float* v0    = (const float*)d_in[4];
    const float* I0    = (const float*)d_in[5];
    float* out = (float*)d_out;
    (void)in_sizes; (void)n_in; (void)out_size; (void)d_ws; (void)ws_size;

    hipLaunchKernelGGL(prep_w,  dim3(8192), dim3(256), 0, stream, Wrec, types);
    hipLaunchKernelGGL(prep_ff, dim3(2048), dim3(256), 0, stream, FF);
    hipLaunchKernelGGL(prep_in, dim3(512),  dim3(256), 0, stream, inp);
    hipLaunchKernelGGL(k_init,  dim3(16),   dim3(256), 0, stream, v0, I0, types, out);
    for (int t = 1; t <= TSTEPS; ++t)
        hipLaunchKernelGGL(k_step, dim3(256), dim3(256), 0, stream, types, out, t);
}

// Round 2
// 10519.371 us; speedup vs baseline: 1.5420x; 1.5420x over previous
//
#include <hip/hip_runtime.h>
#include <stdint.h>

#define N_NEUR 4096
#define N_IN   512
#define BATCH  8
#define TSTEPS 1000
#define KB_REC 128                 // 128 k-blocks of 32 for recurrent W
#define KB_TOT 144                 // + 16 k-blocks for feedforward (K = 4608)
#define STRIDE_OUT (BATCH * TSTEPS * N_NEUR)

#define BETA_E_F 0.95122942450071400910f
#define BETA_I_F 0.90483741803595957316f
#define ALPHA_F  0.81873075307798185867f
#define RC_E_F   (100.0f * (1.0f - BETA_E_F))
#define RC_I_F   (100.0f * (1.0f - BETA_I_F))
#define U_REST_F  (-65.0f)
#define THETA_F   (-50.0f)
#define U_RESET_F (-65.0f)

typedef __attribute__((ext_vector_type(8))) short short8;
typedef __attribute__((ext_vector_type(4))) float f32x4;
typedef __attribute__((ext_vector_type(4))) int   i32x4;

// B-fragment-packed weights: [stripe 256][kb 144][lane 64][j 8] bf16
// element = (kb<128 ? W[k][col]*scale : FF[k-4096][col]), k = kb*32 + (lane>>4)*8 + j, col = stripe*16 + (lane&15)
__device__ __attribute__((aligned(16))) uint16_t g_B[256 * KB_TOT * 512];
__device__ __attribute__((aligned(16))) uint8_t  g_sb[2 * N_NEUR];   // spike bitmask bytes (bit b = batch b), dbuf
__device__ __attribute__((aligned(16))) uint8_t  g_inb[TSTEPS * N_IN]; // input bitmask bytes
__device__ float g_I[BATCH * N_NEUR];
__device__ float g_vr[BATCH * N_NEUR];

__device__ __forceinline__ uint16_t f2bf(float v) {
    uint32_t x = __float_as_uint(v);
    uint32_t r = x + 0x7FFFu + ((x >> 16) & 1u);
    return (uint16_t)(r >> 16);
}

// repack recurrent W into B-fragment layout (one short8 store per thread)
__global__ void prep_w(const float* __restrict__ W, const int* __restrict__ types) {
    int o = blockIdx.x * 256 + threadIdx.x;          // 256*128*64 = 2,097,152 threads
    int lane = o & 63, kb = (o >> 6) & 127, stripe = o >> 13;
    int col = (stripe << 4) + (lane & 15);
    float scale = (types[col] == 1) ? 0.5f : 2.0f;
    int kbase = kb * 32 + ((lane >> 4) & 3) * 8;
    uint32_t u[4];
#pragma unroll
    for (int p = 0; p < 4; ++p) {
        float v0 = W[(size_t)(kbase + 2 * p) * N_NEUR + col] * scale;
        float v1 = W[(size_t)(kbase + 2 * p + 1) * N_NEUR + col] * scale;
        u[p] = (uint32_t)f2bf(v0) | ((uint32_t)f2bf(v1) << 16);
    }
    i32x4 iv = { (int)u[0], (int)u[1], (int)u[2], (int)u[3] };
    ((short8*)g_B)[(stripe * KB_TOT + kb) * 64 + lane] = __builtin_bit_cast(short8, iv);
}

// repack feedforward FF into kb 128..143 of g_B (no scaling)
__global__ void prep_ff(const float* __restrict__ FF) {
    int o = blockIdx.x * 256 + threadIdx.x;          // 256*16*64 = 262,144 threads
    int lane = o & 63, kbl = (o >> 6) & 15, stripe = o >> 10;
    int col = (stripe << 4) + (lane & 15);
    int kbase = kbl * 32 + ((lane >> 4) & 3) * 8;
    uint32_t u[4];
#pragma unroll
    for (int p = 0; p < 4; ++p) {
        float v0 = FF[(size_t)(kbase + 2 * p) * N_NEUR + col];
        float v1 = FF[(size_t)(kbase + 2 * p + 1) * N_NEUR + col];
        u[p] = (uint32_t)f2bf(v0) | ((uint32_t)f2bf(v1) << 16);
    }
    i32x4 iv = { (int)u[0], (int)u[1], (int)u[2], (int)u[3] };
    ((short8*)g_B)[(stripe * KB_TOT + 128 + kbl) * 64 + lane] = __builtin_bit_cast(short8, iv);
}

// bit-pack input spikes: g_inb[t*512+i] bit b = inputs[b][t][i] != 0
__global__ void prep_in(const float* __restrict__ inp) {
    const int total = TSTEPS * N_IN;
    for (int o = blockIdx.x * 256 + threadIdx.x; o < total; o += gridDim.x * 256) {
        int t = o >> 9, i = o & 511;
        uint32_t m = 0;
#pragma unroll
        for (int b = 0; b < 8; ++b) {
            float v = inp[(size_t)(b * TSTEPS + t) * N_IN + i];
            m |= (v != 0.0f ? 1u : 0u) << b;
        }
        g_inb[o] = (uint8_t)m;
    }
}

// step 0: v[1], s[1] from initial state; emits tau=0 outputs; seeds states + spike bytes slot 1
__global__ void k_init(const float* __restrict__ v0p, const float* __restrict__ I0p,
                       const int* __restrict__ types, float* __restrict__ out) {
    int n = blockIdx.x * 256 + threadIdx.x;
    bool exc = (types[n] == 1);
    float beta = exc ? BETA_E_F : BETA_I_F;
    float rc   = exc ? RC_E_F   : RC_I_F;
    uint32_t bits = 0;
#pragma unroll
    for (int b = 0; b < 8; ++b) {
        int gi = b * N_NEUR + n;
        float v0 = v0p[gi], I0 = I0p[gi];
        float v = U_REST_F + (v0 - U_REST_F) * beta + I0 * rc;
        bool s = (v >= THETA_F);
        float vr = s ? U_RESET_F : v;
        out[(size_t)(b * TSTEPS + 0) * N_NEUR + n] = s ? 1.0f : 0.0f;
        out[STRIDE_OUT + (size_t)(b * TSTEPS + 0) * N_NEUR + n] = vr;
        g_vr[gi] = vr;
        g_I[gi]  = I0;
        bits |= (s ? 1u : 0u) << b;
    }
    g_sb[1 * N_NEUR + n] = (uint8_t)bits;
}

// K_t: I[t] = alpha*I[t-1] + s[t]@Wsc + in[t-1]@FF (out I @ t-1); then v/s[t+1] (out @ t)
__global__ void __launch_bounds__(512)
k_step(const int* __restrict__ types, float* __restrict__ out, int t) {
    // swizzled mask words: bytes (k0,k2,k1,k3) per 4-group; [0..1023]=spikes, [1024..1151]=inputs
    __shared__ __attribute__((aligned(16))) uint32_t swz[1152];
    __shared__ __attribute__((aligned(16))) float red[8][64][4];
    __shared__ unsigned long long wb[2];

    const int tid  = threadIdx.x;
    const int lane = tid & 63;
    const int w    = tid >> 6;
    const int blk  = blockIdx.x;
    // XCD-aware: XCD (blk&7) owns 32 contiguous stripes => ~4.5MB B-slab per XCD L2
    const int stripe  = ((blk & 7) << 5) | (blk >> 3);
    const int colbase = stripe << 4;

    {   // stage spike + input mask bytes, middle-byte-swapped per 4-group
        const uint32_t* sp = (const uint32_t*)(g_sb + (t & 1) * N_NEUR);
        const uint32_t* ip = (const uint32_t*)(g_inb + (size_t)(t - 1) * N_IN);
        for (int i = tid; i < 1152; i += 512) {
            uint32_t x = (i < 1024) ? sp[i] : ip[i - 1024];
            swz[i] = (x & 0xFF0000FFu) | ((x & 0x0000FF00u) << 8) | ((x >> 8) & 0x0000FF00u);
        }
    }
    __syncthreads();

    const uint32_t msk = ((lane & 15) < 8) ? 0x00010001u : 0u;  // rows 8..15 are zero-pad
    const int sA = lane & 7, sB = sA + 8;
    const int aoff = (lane >> 4) * 2;                            // u32 index within k-block

    f32x4 acc = {0.f, 0.f, 0.f, 0.f};
    const short8* Bp = (const short8*)g_B + ((size_t)stripe * KB_TOT) * 64 + lane;
    const int kb0 = w * 18;
#pragma unroll 6
    for (int it = 0; it < 18; ++it) {
        int kb = kb0 + it;
        uint32_t w0 = swz[kb * 8 + aoff];
        uint32_t w1 = swz[kb * 8 + aoff + 1];
        uint32_t a0 = ((w0 >> sA) & msk) * 0x3F80u;
        uint32_t a1 = ((w0 >> sB) & msk) * 0x3F80u;
        uint32_t a2 = ((w1 >> sA) & msk) * 0x3F80u;
        uint32_t a3 = ((w1 >> sB) & msk) * 0x3F80u;
        i32x4 ai = { (int)a0, (int)a1, (int)a2, (int)a3 };
        short8 av = __builtin_bit_cast(short8, ai);
        short8 bv = Bp[kb * 64];
        acc = __builtin_amdgcn_mfma_f32_16x16x32_bf16(av, bv, acc, 0, 0, 0);
    }
    *(f32x4*)&red[w][lane][0] = acc;
    __syncthreads();

    if (tid < 128) {
        int b = tid >> 4, nl = tid & 15;
        int rl = (b >> 2) * 16 + nl, rr = b & 3;   // C: row = 4*(lane>>4)+reg, col = lane&15
        float S = 0.f;
#pragma unroll
        for (int q = 0; q < 8; ++q) S += red[q][rl][rr];
        int n  = colbase + nl;
        int gi = b * N_NEUR + n;
        float Inew = g_I[gi] * ALPHA_F + S;
        out[2 * STRIDE_OUT + (size_t)(b * TSTEPS + (t - 1)) * N_NEUR + n] = Inew;
        g_I[gi] = Inew;
        if (t < TSTEPS) {
            bool exc = (types[n] == 1);
            float beta = exc ? BETA_E_F : BETA_I_F;
            float rc   = exc ? RC_E_F   : RC_I_F;
            float vr = g_vr[gi];
            float v = U_REST_F + (vr - U_REST_F) * beta + Inew * rc;
            bool sbit = (v >= THETA_F);
            float vn = sbit ? U_RESET_F : v;
            out[(size_t)(b * TSTEPS + t) * N_NEUR + n] = sbit ? 1.0f : 0.0f;
            out[STRIDE_OUT + (size_t)(b * TSTEPS + t) * N_NEUR + n] = vn;
            g_vr[gi] = vn;
            unsigned long long bal = __ballot(sbit);  // wave0: b0..3, wave1: b4..7
            if ((tid & 63) == 0) wb[tid >> 6] = bal;
        }
    }
    __syncthreads();
    if (t < TSTEPS && tid < 16) {
        unsigned long long b0 = wb[0], b1 = wb[1];
        uint32_t bits = 0;
#pragma unroll
        for (int q = 0; q < 4; ++q) {
            bits |= (uint32_t)((b0 >> (tid + 16 * q)) & 1ull) << q;
            bits |= (uint32_t)((b1 >> (tid + 16 * q)) & 1ull) << (q + 4);
        }
        g_sb[((t + 1) & 1) * N_NEUR + colbase + tid] = (uint8_t)bits;
    }
}

extern "C" void kernel_launch(void* const* d_in, const int* in_sizes, int n_in,
                              void* d_out, int out_size, void* d_ws, size_t ws_size,
                              hipStream_t stream) {
    const int*   types = (const int*)d_in[0];
    const float* Wrec  = (const float*)d_in[1];
    const float* FF    = (const float*)d_in[2];
    const float* inp   = (const float*)d_in[3];
    const float* v0    = (const float*)d_in[4];
    const float* I0    = (const float*)d_in[5];
    float* out = (float*)d_out;
    (void)in_sizes; (void)n_in; (void)out_size; (void)d_ws; (void)ws_size;

    hipLaunchKernelGGL(prep_w,  dim3(8192), dim3(256), 0, stream, Wrec, types);
    hipLaunchKernelGGL(prep_ff, dim3(1024), dim3(256), 0, stream, FF);
    hipLaunchKernelGGL(prep_in, dim3(512),  dim3(256), 0, stream, inp);
    hipLaunchKernelGGL(k_init,  dim3(16),   dim3(256), 0, stream, v0, I0, types, out);
    for (int t = 1; t <= TSTEPS; ++t)
        hipLaunchKernelGGL(k_step, dim3(256), dim3(512), 0, stream, types, out, t);
}